// Round 2
// baseline (1336.295 us; speedup 1.0000x reference)
//
#include <hip/hip_runtime.h>
#include <math.h>

#define PI_F 3.14159265358979323846f

// ---------------------------------------------------------------------------
// Direct 3x3 conv, padding SAME, + bias. Optionally applies BN(scale,shift)+ReLU
// to the INPUT while staging to LDS (ss_in = [scale[CIN], shift[CIN]] or null).
// Each block: one batch n, one group of 32 out-channels, RB rows, full width W.
// Each thread: 2 rows x 32 channels at one x. Emits per-block per-channel
// partial sums/sumsq of the (conv+bias) output for BN statistics.
// Tin/Tout: float or _Float16 (stats always accumulated in fp32 pre-rounding).
// ---------------------------------------------------------------------------
template<typename Tin, typename Tout, int CIN, int W, int RB, int CHUNK>
__global__ __launch_bounds__(256) void conv3x3_bn_kernel(
    const Tin* __restrict__ in, const int H, const int COUT,
    const float* __restrict__ wgt, const float* __restrict__ bias,
    const float* __restrict__ ss_in,
    Tout* __restrict__ out,
    float* __restrict__ partials)
{
    constexpr int LW = W + 2;
    constexpr int LH = RB + 2;
    __shared__ __align__(16) float s_in[CHUNK][LH][LW];
    __shared__ __align__(16) float s_w[CHUNK][9][32];
    __shared__ float s_red[64];

    const int t = threadIdx.x;
    const int x = t % W;
    const int q = t / W;            // row-pair index within tile
    const int tile = blockIdx.x;    // row tile
    const int cg = blockIdx.y;      // out-channel group of 32
    const int n = blockIdx.z;
    const int co0 = cg * 32;
    const int y0 = tile * RB;

    float4 acc0[8], acc1[8];
    #pragma unroll
    for (int i = 0; i < 8; ++i) {
        acc0[i] = make_float4(0.f, 0.f, 0.f, 0.f);
        acc1[i] = make_float4(0.f, 0.f, 0.f, 0.f);
    }

    for (int cb = 0; cb < CIN; cb += CHUNK) {
        __syncthreads();
        // ---- stage input tile (with optional bn+relu) ----
        constexpr int TOT_IN = CHUNK * LH * LW;
        for (int idx = t; idx < TOT_IN; idx += 256) {
            int xl = idx % LW;
            int r1 = idx / LW;
            int yl = r1 % LH;
            int ci = r1 / LH;
            int gy = y0 + yl - 1;
            int gx = xl - 1;
            int c = cb + ci;
            float v = 0.f;
            if (gy >= 0 && gy < H && gx >= 0 && gx < W) {
                v = (float)in[((size_t)(n * CIN + c) * H + gy) * W + gx];
                if (ss_in) v = fmaxf(0.f, v * ss_in[c] + ss_in[CIN + c]);
            }
            s_in[ci][yl][xl] = v;
        }
        // ---- stage weights chunk transposed: [ci][tap][co] ----
        constexpr int TOT_W = CHUNK * 9 * 32;
        for (int idx = t; idx < TOT_W; idx += 256) {
            int co = idx & 31;
            int r2 = idx >> 5;
            int tap = r2 % 9;
            int ci = r2 / 9;
            s_w[ci][tap][co] = wgt[((size_t)(co0 + co) * CIN + cb + ci) * 9 + tap];
        }
        __syncthreads();
        // ---- compute ----
        #pragma unroll 1
        for (int ci = 0; ci < CHUNK; ++ci) {
            #pragma unroll
            for (int ky = 0; ky < 3; ++ky) {
                #pragma unroll
                for (int kx = 0; kx < 3; ++kx) {
                    float iv0 = s_in[ci][2 * q + ky][x + kx];
                    float iv1 = s_in[ci][2 * q + 1 + ky][x + kx];
                    const float4* w4 = reinterpret_cast<const float4*>(&s_w[ci][ky * 3 + kx][0]);
                    #pragma unroll
                    for (int c4 = 0; c4 < 8; ++c4) {
                        float4 wv = w4[c4];
                        acc0[c4].x += wv.x * iv0; acc0[c4].y += wv.y * iv0;
                        acc0[c4].z += wv.z * iv0; acc0[c4].w += wv.w * iv0;
                        acc1[c4].x += wv.x * iv1; acc1[c4].y += wv.y * iv1;
                        acc1[c4].z += wv.z * iv1; acc1[c4].w += wv.w * iv1;
                    }
                }
            }
        }
    }

    if (t < 64) s_red[t] = 0.f;
    __syncthreads();

    const int gy0 = y0 + 2 * q;
    #pragma unroll
    for (int c4 = 0; c4 < 8; ++c4) {
        #pragma unroll
        for (int cc = 0; cc < 4; ++cc) {
            int co = c4 * 4 + cc;
            float bv = bias[co0 + co];
            float v0 = ((const float*)&acc0[c4])[cc] + bv;
            float v1 = ((const float*)&acc1[c4])[cc] + bv;
            size_t ob = ((size_t)(n * COUT + co0 + co) * H + gy0) * W + x;
            out[ob] = (Tout)v0;
            out[ob + W] = (Tout)v1;
            float s = v0 + v1;
            float s2 = v0 * v0 + v1 * v1;
            #pragma unroll
            for (int off = 32; off > 0; off >>= 1) {
                s  += __shfl_xor(s, off);
                s2 += __shfl_xor(s2, off);
            }
            if ((t & 63) == 0) {
                atomicAdd(&s_red[co], s);
                atomicAdd(&s_red[32 + co], s2);
            }
        }
    }
    __syncthreads();
    if (t < 64) {
        int bid = (n * gridDim.y + cg) * gridDim.x + tile;
        partials[(size_t)bid * 64 + t] = s_red[t];
    }
}

// ---------------------------------------------------------------------------
// Reduce per-block partials -> BN scale/shift per channel.
// partials layout: bid = (n*ng + g)*nx + xt, 64 floats (32 sum, 32 sumsq)
// ---------------------------------------------------------------------------
__global__ __launch_bounds__(256) void bn_finalize_kernel(
    const float* __restrict__ partials, int nx, int ng, float inv_count,
    const float* __restrict__ gamma, const float* __restrict__ beta,
    float* __restrict__ ss, int COUT)
{
    int T = 256 / COUT;
    int c = threadIdx.x / T;
    int s = threadIdx.x % T;
    int g = c >> 5, i = c & 31;
    float sum = 0.f, sq = 0.f;
    int total = 256 * nx;
    for (int k = s; k < total; k += T) {
        int n = k / nx, xt = k - n * nx;
        size_t bid = ((size_t)(n * ng + g) * nx + xt) * 64;
        sum += partials[bid + i];
        sq  += partials[bid + 32 + i];
    }
    __shared__ float rs[256], rq[256];
    rs[threadIdx.x] = sum; rq[threadIdx.x] = sq;
    __syncthreads();
    if (s == 0) {
        for (int k2 = 1; k2 < T; ++k2) { sum += rs[threadIdx.x + k2]; sq += rq[threadIdx.x + k2]; }
        float mean = sum * inv_count;
        float var = sq * inv_count - mean * mean;
        float scale = gamma[c] * rsqrtf(var + 1e-5f);
        ss[c] = scale;
        ss[COUT + c] = beta[c] - mean * scale;
    }
}

// ---------------------------------------------------------------------------
// Apply BN+ReLU then 2x2/2 max pool. in: (N,C,2HO,2WO) -> out: (N,C,HO,WO)
// ---------------------------------------------------------------------------
template<typename Tin>
__global__ __launch_bounds__(256) void pool_bn_relu_kernel(
    const Tin* __restrict__ in, const float* __restrict__ ss,
    float* __restrict__ out, int C, int HO, int WO, int total)
{
    for (int idx = blockIdx.x * 256 + threadIdx.x; idx < total; idx += gridDim.x * 256) {
        int x = idx % WO;
        int r = idx / WO;
        int y = r % HO;
        int r2 = r / HO;
        int c = r2 % C;
        int n = r2 / C;
        float scale = ss[c], shift = ss[C + c];
        size_t base = ((size_t)(n * C + c) * (2 * HO) + 2 * y) * (2 * WO) + 2 * x;
        float v0 = fmaxf(0.f, (float)in[base] * scale + shift);
        float v1 = fmaxf(0.f, (float)in[base + 1] * scale + shift);
        float v2 = fmaxf(0.f, (float)in[base + 2 * WO] * scale + shift);
        float v3 = fmaxf(0.f, (float)in[base + 2 * WO + 1] * scale + shift);
        out[idx] = fmaxf(fmaxf(v0, v1), fmaxf(v2, v3));
    }
}

// ---------------------------------------------------------------------------
// fc1 GEMM with K-split: A (256,16384) x W^T (128,16384) -> partials (16,256,128)
// ---------------------------------------------------------------------------
__global__ __launch_bounds__(256) void fc1_partial_kernel(
    const float* __restrict__ A, const float* __restrict__ Bw, float* __restrict__ hp)
{
    __shared__ float As[64][33];
    __shared__ float Bs[32][33];
    const int t = threadIdx.x;
    const int n0 = blockIdx.x * 64;
    const int j0 = blockIdx.y * 32;
    const int k0 = blockIdx.z * 1024;
    const int j = t & 31;
    const int i0 = (t >> 5) * 8;
    float acc[8] = {0.f, 0.f, 0.f, 0.f, 0.f, 0.f, 0.f, 0.f};
    for (int ks = 0; ks < 1024; ks += 32) {
        __syncthreads();
        #pragma unroll
        for (int r = 0; r < 8; ++r) {
            int e = t + 256 * r;
            int row = e >> 5, kk = e & 31;
            As[row][kk] = A[(size_t)(n0 + row) * 16384 + k0 + ks + kk];
        }
        #pragma unroll
        for (int r = 0; r < 4; ++r) {
            int e = t + 256 * r;
            int row = e >> 5, kk = e & 31;
            Bs[row][kk] = Bw[(size_t)(j0 + row) * 16384 + k0 + ks + kk];
        }
        __syncthreads();
        #pragma unroll
        for (int kk = 0; kk < 32; ++kk) {
            float bv = Bs[j][kk];
            #pragma unroll
            for (int i = 0; i < 8; ++i) acc[i] += As[i0 + i][kk] * bv;
        }
    }
    #pragma unroll
    for (int i = 0; i < 8; ++i)
        hp[((size_t)blockIdx.z * 256 + n0 + i0 + i) * 128 + j0 + j] = acc[i];
}

__global__ __launch_bounds__(256) void fc1_reduce_kernel(
    const float* __restrict__ hp, const float* __restrict__ bias, float* __restrict__ h1)
{
    int gid = blockIdx.x * 256 + threadIdx.x;   // 32768
    int n = gid >> 7, j = gid & 127;
    float s = bias[j];
    #pragma unroll
    for (int kc = 0; kc < 16; ++kc) s += hp[((size_t)kc * 256 + n) * 128 + j];
    h1[gid] = fmaxf(0.f, s);
}

// ---------------------------------------------------------------------------
// fc2: (256,128) x (10,128)^T + b -> xq (256,10). One wave per batch element.
// ---------------------------------------------------------------------------
__global__ __launch_bounds__(64) void fc2_kernel(
    const float* __restrict__ h1, const float* __restrict__ w,
    const float* __restrict__ b, float* __restrict__ xq)
{
    int n = blockIdx.x, l = threadIdx.x;
    float a0 = h1[n * 128 + l], a1 = h1[n * 128 + 64 + l];
    float p[10];
    #pragma unroll
    for (int j = 0; j < 10; ++j)
        p[j] = w[j * 128 + l] * a0 + w[j * 128 + 64 + l] * a1;
    #pragma unroll
    for (int j = 0; j < 10; ++j) {
        #pragma unroll
        for (int off = 32; off > 0; off >>= 1) p[j] += __shfl_xor(p[j], off);
    }
    if (l == 0) {
        #pragma unroll
        for (int j = 0; j < 10; ++j) xq[n * 10 + j] = p[j] + b[j];
    }
}

// ---------------------------------------------------------------------------
// 10-qubit state-vector sim (1024 amplitudes in LDS) + Z expectations + head.
// One block per batch element.
// ---------------------------------------------------------------------------
__global__ __launch_bounds__(256) void quantum_head_kernel(
    const float* __restrict__ xq, const float* __restrict__ qw,
    const float* __restrict__ head_w, const float* __restrict__ head_b,
    float* __restrict__ outp)
{
    __shared__ float sr[1024], si[1024];
    const int n = blockIdx.x, t = threadIdx.x;
    for (int i = t; i < 1024; i += 256) { sr[i] = 0.f; si[i] = 0.f; }
    __syncthreads();
    if (t == 0) sr[0] = 1.f;
    __syncthreads();

    // RY(pi*xq) encoding, wire w acts on bit (9-w)
    for (int w = 0; w < 10; ++w) {
        float th = 0.5f * PI_F * xq[n * 10 + w];
        float c = cosf(th), s = sinf(th);
        int k = 9 - w, kb = 1 << k;
        #pragma unroll
        for (int pp = 0; pp < 2; ++pp) {
            int p = t + 256 * pp;
            int i0 = ((p >> k) << (k + 1)) | (p & (kb - 1));
            int i1 = i0 | kb;
            float ar = sr[i0], br = sr[i1], ai = si[i0], bi = si[i1];
            sr[i0] = c * ar - s * br;  si[i0] = c * ai - s * bi;
            sr[i1] = s * ar + c * br;  si[i1] = s * ai + c * bi;
        }
        __syncthreads();
    }

    // 6 layers of Rot gates + CNOT-ring permutation
    for (int l = 0; l < 6; ++l) {
        for (int w = 0; w < 10; ++w) {
            const float* qp = qw + (l * 10 + w) * 3;
            float phi = qp[0], th = qp[1], om = qp[2];
            float c = cosf(0.5f * th), s = sinf(0.5f * th);
            float apo = 0.5f * (phi + om), amo = 0.5f * (phi - om);
            float cpo = cosf(apo), spo = sinf(apo);
            float cmo = cosf(amo), smo = sinf(amo);
            float m00r = cpo * c,  m00i = -spo * c;
            float m01r = -cmo * s, m01i = -smo * s;
            float m10r = cmo * s,  m10i = -smo * s;
            float m11r = cpo * c,  m11i = spo * c;
            int k = 9 - w, kb = 1 << k;
            #pragma unroll
            for (int pp = 0; pp < 2; ++pp) {
                int p = t + 256 * pp;
                int i0 = ((p >> k) << (k + 1)) | (p & (kb - 1));
                int i1 = i0 | kb;
                float ar = sr[i0], ai = si[i0], br = sr[i1], bi = si[i1];
                sr[i0] = m00r * ar - m00i * ai + m01r * br - m01i * bi;
                si[i0] = m00r * ai + m00i * ar + m01r * bi + m01i * br;
                sr[i1] = m10r * ar - m10i * ai + m11r * br - m11i * bi;
                si[i1] = m10r * ai + m10i * ar + m11r * bi + m11i * br;
            }
            __syncthreads();
        }
        // state = state[:, perm]; perm[i] = pg_0(pg_1(...pg_9(i)))
        int r = l % 9 + 1;
        float tr[4], ti[4];
        #pragma unroll
        for (int si_ = 0; si_ < 4; ++si_) {
            int i = t + 256 * si_;
            int jdx = i;
            #pragma unroll
            for (int w = 9; w >= 0; --w) {
                int tt = (w + r) % 10;
                int pc = 9 - w, pt = 9 - tt;
                jdx ^= ((jdx >> pc) & 1) << pt;
            }
            tr[si_] = sr[jdx]; ti[si_] = si[jdx];
        }
        __syncthreads();
        #pragma unroll
        for (int si_ = 0; si_ < 4; ++si_) {
            int i = t + 256 * si_;
            sr[i] = tr[si_]; si[i] = ti[si_];
        }
        __syncthreads();
    }

    // Z expectations: q[k] = sum_i probs[i] * (1 - 2*bit(i, 9-k))
    float pk[10];
    #pragma unroll
    for (int w = 0; w < 10; ++w) pk[w] = 0.f;
    #pragma unroll
    for (int si_ = 0; si_ < 4; ++si_) {
        int i = t + 256 * si_;
        float pr = sr[i] * sr[i] + si[i] * si[i];
        #pragma unroll
        for (int w = 0; w < 10; ++w)
            pk[w] += ((i >> (9 - w)) & 1) ? -pr : pr;
    }
    __syncthreads();
    #pragma unroll
    for (int w = 0; w < 10; ++w) {
        #pragma unroll
        for (int off = 32; off > 0; off >>= 1) pk[w] += __shfl_xor(pk[w], off);
    }
    int wave = t >> 6, lane = t & 63;
    if (lane == 0) {
        #pragma unroll
        for (int w = 0; w < 10; ++w) sr[wave * 10 + w] = pk[w];
    }
    __syncthreads();
    if (t < 10) si[t] = sr[t] + sr[10 + t] + sr[20 + t] + sr[30 + t];
    __syncthreads();
    if (t < 10) {
        float o = head_b[t];
        #pragma unroll
        for (int kk = 0; kk < 10; ++kk) o += si[kk] * head_w[t * 10 + kk];
        outp[n * 10 + t] = o;
    }
}

// ---------------------------------------------------------------------------
// Workspace layout (floats, total 42,074,480 fl = 168.3 MB):
//   R0 [0, 16,777,216):        c1out as _Float16 (33.5M halves) -> later c4out fp32
//   R1 [16,777,216, 33,554,432): c2out as _Float16 -> later c3out fp32
//   R2 [33,554,432, 41,943,040): pool1out fp32 (8.4M) -> later pool2out(4.2M)+hp+h1+xq
//   R3 [41,943,040, ...):      part (131,072) + ss1(64)+ss2(64)+ss3(128)+ss4(128)
// ---------------------------------------------------------------------------
extern "C" void kernel_launch(void* const* d_in, const int* in_sizes, int n_in,
                              void* d_out, int out_size, void* d_ws, size_t ws_size,
                              hipStream_t stream)
{
    const float* x   = (const float*)d_in[0];
    const float* c1w = (const float*)d_in[1];  const float* c1b = (const float*)d_in[2];
    const float* g1  = (const float*)d_in[3];  const float* b1  = (const float*)d_in[4];
    const float* c2w = (const float*)d_in[5];  const float* c2b = (const float*)d_in[6];
    const float* g2  = (const float*)d_in[7];  const float* b2  = (const float*)d_in[8];
    const float* c3w = (const float*)d_in[9];  const float* c3b = (const float*)d_in[10];
    const float* g3  = (const float*)d_in[11]; const float* b3  = (const float*)d_in[12];
    const float* c4w = (const float*)d_in[13]; const float* c4b = (const float*)d_in[14];
    const float* g4  = (const float*)d_in[15]; const float* b4  = (const float*)d_in[16];
    const float* f1w = (const float*)d_in[17]; const float* f1b = (const float*)d_in[18];
    const float* f2w = (const float*)d_in[19]; const float* f2b = (const float*)d_in[20];
    const float* qw  = (const float*)d_in[21];
    const float* hw  = (const float*)d_in[22]; const float* hb  = (const float*)d_in[23];

    float* ws = (float*)d_ws;
    float*     R0f  = ws;                                  // 16,777,216 floats
    _Float16*  R0h  = (_Float16*)ws;                       // 33,554,432 halves
    float*     R1f  = ws + 16777216;
    _Float16*  R1h  = (_Float16*)(ws + 16777216);
    float*     R2   = ws + 33554432;                       // 8,388,608 floats
    float*     part = ws + 41943040;                       // 131,072
    float*     ss1  = part + 131072;                       // 64
    float*     ss2  = ss1 + 64;                            // 64
    float*     ss3  = ss2 + 64;                            // 128
    float*     ss4  = ss3 + 128;                           // 128

    float* pool1 = R2;                                     // 8,388,608 fl
    float* pool2 = R2;                                     // 4,194,304 fl (pool1 dead)
    float* hp    = R2 + 4194304;                           // 524,288 fl
    float* h1    = R2 + 4718592;                           // 32,768 fl
    float* xqv   = R2 + 4751360;                           // 2,560 fl

    // conv1: x (256,3,64,64) -> R0h (256,32,64,64) fp16
    conv3x3_bn_kernel<float, _Float16, 3, 64, 8, 3><<<dim3(8, 1, 256), 256, 0, stream>>>(
        x, 64, 32, c1w, c1b, nullptr, R0h, part);
    bn_finalize_kernel<<<1, 256, 0, stream>>>(part, 8, 1, 1.f / 1048576.f, g1, b1, ss1, 32);

    // conv2: bn1+relu(R0h) -> R1h (256,32,64,64) fp16
    conv3x3_bn_kernel<_Float16, _Float16, 32, 64, 8, 8><<<dim3(8, 1, 256), 256, 0, stream>>>(
        R0h, 64, 32, c2w, c2b, ss1, R1h, part);
    bn_finalize_kernel<<<1, 256, 0, stream>>>(part, 8, 1, 1.f / 1048576.f, g2, b2, ss2, 32);

    // pool1: bn2+relu(R1h) pooled -> pool1 (256,32,32,32) fp32
    pool_bn_relu_kernel<_Float16><<<4096, 256, 0, stream>>>(R1h, ss2, pool1, 32, 32, 32, 8388608);

    // conv3: pool1 (pre-activated) -> R1f (256,64,32,32) fp32  (c2out dead)
    conv3x3_bn_kernel<float, float, 32, 32, 16, 8><<<dim3(2, 2, 256), 256, 0, stream>>>(
        pool1, 32, 64, c3w, c3b, nullptr, R1f, part);
    bn_finalize_kernel<<<1, 256, 0, stream>>>(part, 2, 2, 1.f / 262144.f, g3, b3, ss3, 64);

    // conv4: bn3+relu(R1f) -> R0f (256,64,32,32) fp32  (c1out dead)
    conv3x3_bn_kernel<float, float, 64, 32, 16, 8><<<dim3(2, 2, 256), 256, 0, stream>>>(
        R1f, 32, 64, c4w, c4b, ss3, R0f, part);
    bn_finalize_kernel<<<1, 256, 0, stream>>>(part, 2, 2, 1.f / 262144.f, g4, b4, ss4, 64);

    // pool2: bn4+relu(R0f) pooled -> pool2 (256,64,16,16) fp32 (pool1 dead)
    pool_bn_relu_kernel<float><<<4096, 256, 0, stream>>>(R0f, ss4, pool2, 64, 16, 16, 4194304);

    // fc1 (K-split) + reduce(+bias+relu) -> h1 (256,128)
    fc1_partial_kernel<<<dim3(4, 4, 16), 256, 0, stream>>>(pool2, f1w, hp);
    fc1_reduce_kernel<<<128, 256, 0, stream>>>(hp, f1b, h1);

    // fc2 -> xq (256,10)
    fc2_kernel<<<256, 64, 0, stream>>>(h1, f2w, f2b, xqv);

    // quantum circuit + head -> out (256,10)
    quantum_head_kernel<<<256, 256, 0, stream>>>(xqv, qw, hw, hb, (float*)d_out);
}